// Round 1
// 1416.228 us; speedup vs baseline: 1.1288x; 1.1288x over previous
//
#include <hip/hip_runtime.h>
#include <hip/hip_bf16.h>
#include <stdint.h>

// LeWin window attention, fused: qkv GEMM -> per-head attention -> proj GEMM.
// v2: one block per window, but 1024 threads (16 waves) and LDS cut 152->134 KB
// so the whole block is co-resident at 4 waves/SIMD (was 2). Latency-bound fix.
//  - sP lives in the dead x-staging region (XOR-swizzled [4][64][64]).
//  - O held in regs through P3, staged into dead sQK for P4.
//  - softmax without max-subtract (logits bounded ~ +-8; exp2 safe in f32),
//    normalization deferred to the O epilogue (same (quad,r)->row mapping).
//  - bias table pre-scaled by log2e in prep; v_exp_f32 / v_rcp_f32 builtins.
//  - P2/P4 kk-outer: A-fragments read from LDS once per kk (3x fewer ds_read_b128).

typedef __attribute__((ext_vector_type(8))) short bf16x8;
typedef __attribute__((ext_vector_type(4))) float f32x4;

#define QK_LD 520   // row stride (elems) of q|k LDS tile [64][512] (+8 pad)
#define VT_LD 72    // row stride of v-transposed tile [256][64] (+8 pad)
#define X_LD  264   // row stride of x tile [64][256] (+8 pad); also out-transit in sQK
#define SQK_ELEMS (64 * QK_LD)
#define SVT_ELEMS (256 * VT_LD)
#define SX_ELEMS  (64 * X_LD)
#define SMEM_ELEMS (SQK_ELEMS + SVT_ELEMS + SX_ELEMS)
#define SMEM_BYTES (SMEM_ELEMS * 2)   // 137216 B: one 16-wave block per CU

__device__ __forceinline__ unsigned short f2bf(float x) {   // RNE via HW cvt
  union { __hip_bfloat16 h; unsigned short u; } c;
  c.h = __float2bfloat16(x);
  return c.u;
}
__device__ __forceinline__ float bf2f(unsigned short u) {
  union { unsigned int u; float f; } v; v.u = ((unsigned int)u) << 16;
  return v.f;
}

__global__ void prep_kernel(const float* __restrict__ qkv_w,
                            const float* __restrict__ proj_w,
                            const float* __restrict__ table,
                            const int* __restrict__ idx,
                            unsigned short* __restrict__ wq,
                            unsigned short* __restrict__ wp,
                            unsigned short* __restrict__ bm) {
  int i = blockIdx.x * 256 + threadIdx.x;          // grid sized to exactly 294912
  if (i < 196608) {
    wq[i] = f2bf(qkv_w[i]);
  } else if (i < 262144) {
    int j = i - 196608;
    wp[j] = f2bf(proj_w[j]);
  } else {
    int k = i - 262144;                            // k = h*4096 + r*64 + c, k < 32768
    int h = k >> 12;
    int rc = k & 4095;
    // pre-scale by log2(e): softmax runs entirely in the exp2 domain
    bm[k] = f2bf(table[idx[rc] * 8 + h] * 1.4426950408889634f);
  }
}

__launch_bounds__(1024, 4)
__global__ void lewin_kernel(const float* __restrict__ x,
                             const unsigned short* __restrict__ wq,   // [768][256] bf16
                             const float* __restrict__ qkv_b,
                             const unsigned short* __restrict__ wp,   // [256][256] bf16
                             const float* __restrict__ proj_b,
                             const unsigned short* __restrict__ bm,   // [8][64][64] bf16 (x log2e)
                             float* __restrict__ out) {
  extern __shared__ __align__(16) unsigned short smem[];
  unsigned short* sQK = smem;                       // [64][QK_LD] q|k; later out-transit [64][X_LD]
  unsigned short* sVT = smem + SQK_ELEMS;           // [256][VT_LD] v transposed [h*32+d][token]
  unsigned short* sX  = sVT + SVT_ELEMS;            // [64][X_LD] x; later P tiles [4][64][64] swizzled

  const int b    = blockIdx.x;
  const int tid  = threadIdx.x;
  const int wv   = tid >> 6;        // wave 0..15
  const int lane = tid & 63;
  const int l16  = lane & 15;
  const int quad = lane >> 4;
  const f32x4 fz = {0.0f, 0.0f, 0.0f, 0.0f};

  // ---------- Phase 1: stage x window (f32 HBM -> bf16 LDS), fully coalesced ----------
  const float* xb = x + (size_t)b * 16384;
  #pragma unroll
  for (int it = 0; it < 4; ++it) {
    int f = (it * 1024 + tid) * 4;                  // flat float index in window
    float4 v = *(const float4*)(xb + f);
    int row = f >> 8, col = f & 255;
    ushort4 u;
    u.x = f2bf(v.x); u.y = f2bf(v.y); u.z = f2bf(v.z); u.w = f2bf(v.w);
    *(ushort4*)(sX + row * X_LD + col) = u;
  }
  __syncthreads();

  // ---------- Phase 2: qkv = x @ Wqkv^T (+b). Wave wv owns output cols [48wv, 48wv+48) ----
  {
    f32x4 acc[3][4];
    #pragma unroll
    for (int nt = 0; nt < 3; ++nt)
      #pragma unroll
      for (int m = 0; m < 4; ++m) acc[nt][m] = fz;
    const int colb = wv * 48;
    #pragma unroll
    for (int kk = 0; kk < 8; ++kk) {
      bf16x8 a[4];                                  // A-frags read once per kk, shared by 3 nt
      #pragma unroll
      for (int m = 0; m < 4; ++m)
        a[m] = *(const bf16x8*)(sX + (16 * m + l16) * X_LD + kk * 32 + quad * 8);
      #pragma unroll
      for (int nt = 0; nt < 3; ++nt) {
        bf16x8 bg = *(const bf16x8*)(wq + (size_t)(colb + nt * 16 + l16) * 256 + kk * 32 + quad * 8);
        #pragma unroll
        for (int m = 0; m < 4; ++m)
          acc[nt][m] = __builtin_amdgcn_mfma_f32_16x16x32_bf16(a[m], bg, acc[nt][m], 0, 0, 0);
      }
    }
    #pragma unroll
    for (int nt = 0; nt < 3; ++nt) {
      int col = colb + nt * 16 + l16;
      float bc = qkv_b[col];
      #pragma unroll
      for (int m = 0; m < 4; ++m) {
        int row0 = 16 * m + quad * 4;
        if (col < 512) {                            // q,k: row-major [token][col]
          #pragma unroll
          for (int r = 0; r < 4; ++r)
            sQK[(row0 + r) * QK_LD + col] = f2bf(acc[nt][m][r] + bc);
        } else {                                    // v: transposed [col-512][token], 4 contig
          int c = col - 512;
          ushort4 u;
          u.x = f2bf(acc[nt][m][0] + bc); u.y = f2bf(acc[nt][m][1] + bc);
          u.z = f2bf(acc[nt][m][2] + bc); u.w = f2bf(acc[nt][m][3] + bc);
          *(ushort4*)(sVT + c * VT_LD + row0) = u;
        }
      }
    }
  }
  __syncthreads();

  // ---------- Phase 3: attention. Wave -> (M-tile mt, head-pair hp). No intra-loop barriers:
  // each wave touches only its own 16 P rows and its own rows/heads. x region is dead -> P. ----
  const int mt = wv & 3;
  const int hp = wv >> 2;                           // 0..3, heads {2hp, 2hp+1}
  unsigned short* sP = sX + hp * 4096;              // [64][64], XOR-swizzled (idx ^= (row&7)<<3)
  const float s2 = 0.17677669529663687f * 1.4426950408889634f;   // HEAD_DIM^-0.5 * log2(e)
  f32x4 o[2][2] = {{fz, fz}, {fz, fz}};
  float inv[2][4];

  #pragma unroll
  for (int hh = 0; hh < 2; ++hh) {
    int h = hp * 2 + hh;
    bf16x8 qa = *(const bf16x8*)(sQK + (16 * mt + l16) * QK_LD + h * 32 + quad * 8);
    float e[4][4];                                  // [nt][r]: exp(logit), no max-subtract
    #pragma unroll
    for (int nt = 0; nt < 4; ++nt) {
      bf16x8 kb = *(const bf16x8*)(sQK + (nt * 16 + l16) * QK_LD + 256 + h * 32 + quad * 8);
      f32x4 a = __builtin_amdgcn_mfma_f32_16x16x32_bf16(qa, kb, fz, 0, 0, 0);
      const unsigned short* bmr = bm + (h * 64 + 16 * mt + quad * 4) * 64 + nt * 16 + l16;
      #pragma unroll
      for (int r = 0; r < 4; ++r)
        e[nt][r] = __builtin_amdgcn_exp2f(fmaf(a[r], s2, bf2f(bmr[r * 64])));
    }
    // row sum (row's 64 values live in the 16 lanes of this quad, 4 per lane)
    #pragma unroll
    for (int r = 0; r < 4; ++r) {
      float s = (e[0][r] + e[1][r]) + (e[2][r] + e[3][r]);
      #pragma unroll
      for (int sft = 1; sft < 16; sft <<= 1) s += __shfl_xor(s, sft, 64);
      inv[hh][r] = __builtin_amdgcn_rcpf(s);        // normalization deferred to O epilogue
      int row = 16 * mt + quad * 4 + r;
      int swz = (row & 7) << 3;
      unsigned short* pd = sP + row * 64;
      pd[(l16 + 0) ^ swz]  = f2bf(e[0][r]);
      pd[(l16 + 16) ^ swz] = f2bf(e[1][r]);
      pd[(l16 + 32) ^ swz] = f2bf(e[2][r]);
      pd[(l16 + 48) ^ swz] = f2bf(e[3][r]);
    }
    // PV: o_h[16x32] += P~[16x64] @ V[64x32]   (P~ unnormalized)
    int prow = 16 * mt + l16;
    int pswz = (prow & 7) << 3;
    #pragma unroll
    for (int kk = 0; kk < 2; ++kk) {
      bf16x8 pa  = *(const bf16x8*)(sP + prow * 64 + ((kk * 32 + quad * 8) ^ pswz));
      bf16x8 vb0 = *(const bf16x8*)(sVT + (h * 32 + l16) * VT_LD + kk * 32 + quad * 8);
      bf16x8 vb1 = *(const bf16x8*)(sVT + (h * 32 + 16 + l16) * VT_LD + kk * 32 + quad * 8);
      o[hh][0] = __builtin_amdgcn_mfma_f32_16x16x32_bf16(pa, vb0, o[hh][0], 0, 0, 0);
      o[hh][1] = __builtin_amdgcn_mfma_f32_16x16x32_bf16(pa, vb1, o[hh][1], 0, 0, 0);
    }
  }
  __syncthreads();                                  // all q/k reads done -> sQK reusable

  // ---------- Phase 3.5: stage attn-out (normalized) into dead sQK region ----------
  unsigned short* sOut = sQK;
  #pragma unroll
  for (int hh = 0; hh < 2; ++hh) {
    int h = hp * 2 + hh;
    #pragma unroll
    for (int r = 0; r < 4; ++r) {
      int orow = 16 * mt + quad * 4 + r;
      sOut[orow * X_LD + h * 32 + l16]      = f2bf(o[hh][0][r] * inv[hh][r]);
      sOut[orow * X_LD + h * 32 + 16 + l16] = f2bf(o[hh][1][r] * inv[hh][r]);
    }
  }
  __syncthreads();

  // ---------- Phase 4: final = attn_out @ Wproj^T (+b). Wave wv owns cols [16wv, 16wv+16) ----
  float* ob = out + (size_t)b * 16384;
  const int col = wv * 16 + l16;
  f32x4 acc[4] = {fz, fz, fz, fz};
  #pragma unroll
  for (int kk = 0; kk < 8; ++kk) {
    bf16x8 bg = *(const bf16x8*)(wp + (size_t)col * 256 + kk * 32 + quad * 8);
    #pragma unroll
    for (int m = 0; m < 4; ++m) {
      bf16x8 a = *(const bf16x8*)(sOut + (16 * m + l16) * X_LD + kk * 32 + quad * 8);
      acc[m] = __builtin_amdgcn_mfma_f32_16x16x32_bf16(a, bg, acc[m], 0, 0, 0);
    }
  }
  float pb = proj_b[col];
  #pragma unroll
  for (int m = 0; m < 4; ++m)
    #pragma unroll
    for (int r = 0; r < 4; ++r)
      ob[(16 * m + quad * 4 + r) * 256 + col] = acc[m][r] + pb;
}

extern "C" void kernel_launch(void* const* d_in, const int* in_sizes, int n_in,
                              void* d_out, int out_size, void* d_ws, size_t ws_size,
                              hipStream_t stream) {
  const float* x      = (const float*)d_in[0];
  const float* qkv_w  = (const float*)d_in[1];   // [768][256]
  const float* qkv_b  = (const float*)d_in[2];   // [768]
  const float* proj_w = (const float*)d_in[3];   // [256][256]
  const float* proj_b = (const float*)d_in[4];   // [256]
  const float* table  = (const float*)d_in[5];   // [225][8]
  const int*   idx    = (const int*)d_in[6];     // [64][64]
  float* out = (float*)d_out;

  // ws layout: bf16 qkv_w (393216 B) | bf16 proj_w (131072 B) | bf16 bias [8][64][64] (65536 B)
  unsigned short* wq = (unsigned short*)d_ws;
  unsigned short* wp = wq + 196608;
  unsigned short* bm = wp + 65536;

  (void)hipFuncSetAttribute((const void*)lewin_kernel,
                            hipFuncAttributeMaxDynamicSharedMemorySize, SMEM_BYTES);

  prep_kernel<<<1152, 256, 0, stream>>>(qkv_w, proj_w, table, idx, wq, wp, bm);
  lewin_kernel<<<8192, 1024, SMEM_BYTES, stream>>>(x, wq, qkv_b, wp, proj_b, bm, out);
}

// Round 2
// 1329.638 us; speedup vs baseline: 1.2023x; 1.0651x over previous
//
#include <hip/hip_runtime.h>
#include <hip/hip_bf16.h>
#include <stdint.h>

// LeWin window attention, fused: qkv GEMM -> per-head attention -> proj GEMM.
// v3: latency-hiding pass on v2's 16-wave structure.
//  - P2 B-frags software-pipelined (1-deep rotating prefetch) instead of
//    load-before-use (v2 exposed ~24 serial L2 round-trips per wave).
//  - P4 weight frags + proj bias prefetched right after the P2->P3 barrier
//    (in flight across all of phase 3); rel-bias prefetched into regs.
//  - softmax row-sum via 2 MFMAs against a ones-fragment (sums land in the
//    same (quad,r) layout as the O accumulator) -- removes 32 serial shfls.
//  - attn-out written straight into the wave's OWN q rows of sQK (only this
//    wave ever reads them) -> P3.5 barrier eliminated (4 -> 3 barriers).

typedef __attribute__((ext_vector_type(8))) short bf16x8;
typedef __attribute__((ext_vector_type(4))) float f32x4;

#define QK_LD 520   // row stride (elems) of q|k LDS tile [64][512] (+8 pad)
#define VT_LD 72    // row stride of v-transposed tile [256][64] (+8 pad)
#define X_LD  264   // row stride of x tile [64][256] (+8 pad)
#define SQK_ELEMS (64 * QK_LD)
#define SVT_ELEMS (256 * VT_LD)
#define SX_ELEMS  (64 * X_LD)
#define SMEM_ELEMS (SQK_ELEMS + SVT_ELEMS + SX_ELEMS)
#define SMEM_BYTES (SMEM_ELEMS * 2)   // 137216 B: one 16-wave block per CU

__device__ __forceinline__ unsigned short f2bf(float x) {   // RNE via HW cvt
  union { __hip_bfloat16 h; unsigned short u; } c;
  c.h = __float2bfloat16(x);
  return c.u;
}
__device__ __forceinline__ float bf2f(unsigned short u) {
  union { unsigned int u; float f; } v; v.u = ((unsigned int)u) << 16;
  return v.f;
}

__global__ void prep_kernel(const float* __restrict__ qkv_w,
                            const float* __restrict__ proj_w,
                            const float* __restrict__ table,
                            const int* __restrict__ idx,
                            unsigned short* __restrict__ wq,
                            unsigned short* __restrict__ wp,
                            unsigned short* __restrict__ bm) {
  int i = blockIdx.x * 256 + threadIdx.x;          // grid sized to exactly 294912
  if (i < 196608) {
    wq[i] = f2bf(qkv_w[i]);
  } else if (i < 262144) {
    int j = i - 196608;
    wp[j] = f2bf(proj_w[j]);
  } else {
    int k = i - 262144;                            // k = h*4096 + r*64 + c, k < 32768
    int h = k >> 12;
    int rc = k & 4095;
    // pre-scale by log2(e): softmax runs entirely in the exp2 domain
    bm[k] = f2bf(table[idx[rc] * 8 + h] * 1.4426950408889634f);
  }
}

__launch_bounds__(1024, 4)
__global__ void lewin_kernel(const float* __restrict__ x,
                             const unsigned short* __restrict__ wq,   // [768][256] bf16
                             const float* __restrict__ qkv_b,
                             const unsigned short* __restrict__ wp,   // [256][256] bf16
                             const float* __restrict__ proj_b,
                             const unsigned short* __restrict__ bm,   // [8][64][64] bf16 (x log2e)
                             float* __restrict__ out) {
  extern __shared__ __align__(16) unsigned short smem[];
  unsigned short* sQK = smem;                       // [64][QK_LD] q|k; q rows become attn-out
  unsigned short* sVT = smem + SQK_ELEMS;           // [256][VT_LD] v transposed [h*32+d][token]
  unsigned short* sX  = sVT + SVT_ELEMS;            // [64][X_LD] x; later P tiles [4][64][64] swz

  const int b    = blockIdx.x;
  const int tid  = threadIdx.x;
  const int wv   = tid >> 6;        // wave 0..15
  const int lane = tid & 63;
  const int l16  = lane & 15;
  const int quad = lane >> 4;
  const int mt   = wv & 3;          // phase-3 M-tile
  const int hp   = wv >> 2;         // phase-3 head pair
  const f32x4 fz = {0.0f, 0.0f, 0.0f, 0.0f};

  // ---------- issue x loads, then P2's first B-frags + qkv bias (deep cover) ----------
  const float* xb = x + (size_t)b * 16384;
  float4 xv[4];
  #pragma unroll
  for (int it = 0; it < 4; ++it)
    xv[it] = *(const float4*)(xb + (size_t)(it * 1024 + tid) * 4);

  const unsigned short* wb2 = wq + (size_t)(wv * 48 + l16) * 256 + quad * 8;
  bf16x8 bb[2][3];
  #pragma unroll
  for (int nt = 0; nt < 3; ++nt)
    bb[0][nt] = *(const bf16x8*)(wb2 + nt * 4096);
  float qb[3];
  #pragma unroll
  for (int nt = 0; nt < 3; ++nt)
    qb[nt] = qkv_b[wv * 48 + nt * 16 + l16];

  // ---------- Phase 1: stage x window (f32 -> bf16 LDS) ----------
  #pragma unroll
  for (int it = 0; it < 4; ++it) {
    int f = (it * 1024 + tid) * 4;
    int row = f >> 8, col = f & 255;
    ushort4 u;
    u.x = f2bf(xv[it].x); u.y = f2bf(xv[it].y); u.z = f2bf(xv[it].z); u.w = f2bf(xv[it].w);
    *(ushort4*)(sX + row * X_LD + col) = u;
  }
  __syncthreads();

  // ---------- Phase 2: qkv = x @ Wqkv^T (+b). Wave owns cols [48wv, 48wv+48).
  // kk-outer, acc[3][4]; next-kk B-frags prefetched during current MFMAs. ----------
  {
    f32x4 acc[3][4];
    #pragma unroll
    for (int nt = 0; nt < 3; ++nt)
      #pragma unroll
      for (int m = 0; m < 4; ++m) acc[nt][m] = fz;
    #pragma unroll
    for (int kk = 0; kk < 8; ++kk) {
      if (kk < 7) {
        #pragma unroll
        for (int nt = 0; nt < 3; ++nt)
          bb[(kk + 1) & 1][nt] = *(const bf16x8*)(wb2 + nt * 4096 + (kk + 1) * 32);
      }
      bf16x8 a[4];
      #pragma unroll
      for (int m = 0; m < 4; ++m)
        a[m] = *(const bf16x8*)(sX + (16 * m + l16) * X_LD + kk * 32 + quad * 8);
      #pragma unroll
      for (int nt = 0; nt < 3; ++nt)
        #pragma unroll
        for (int m = 0; m < 4; ++m)
          acc[nt][m] = __builtin_amdgcn_mfma_f32_16x16x32_bf16(a[m], bb[kk & 1][nt], acc[nt][m], 0, 0, 0);
    }
    #pragma unroll
    for (int nt = 0; nt < 3; ++nt) {
      int col = wv * 48 + nt * 16 + l16;
      float bc = qb[nt];
      #pragma unroll
      for (int m = 0; m < 4; ++m) {
        int row0 = 16 * m + quad * 4;
        if (col < 512) {                            // q,k: row-major [token][col]
          #pragma unroll
          for (int r = 0; r < 4; ++r)
            sQK[(row0 + r) * QK_LD + col] = f2bf(acc[nt][m][r] + bc);
        } else {                                    // v: transposed [col-512][token], 4 contig
          int c = col - 512;
          ushort4 u;
          u.x = f2bf(acc[nt][m][0] + bc); u.y = f2bf(acc[nt][m][1] + bc);
          u.z = f2bf(acc[nt][m][2] + bc); u.w = f2bf(acc[nt][m][3] + bc);
          *(ushort4*)(sVT + c * VT_LD + row0) = u;
        }
      }
    }
  }

  // ---------- prefetch rel-bias for this wave's (mt, hp) into regs ----------
  unsigned short bvx[2][4][4];
  #pragma unroll
  for (int hh = 0; hh < 2; ++hh) {
    const unsigned short* bmr0 = bm + ((hp * 2 + hh) * 64 + 16 * mt + quad * 4) * 64 + l16;
    #pragma unroll
    for (int nt = 0; nt < 4; ++nt)
      #pragma unroll
      for (int r = 0; r < 4; ++r)
        bvx[hh][nt][r] = bmr0[r * 64 + nt * 16];
  }
  __syncthreads();

  // ---------- prefetch P4 weights + bias (in flight across all of phase 3) ----------
  bf16x8 pb4[8];
  const unsigned short* wr4 = wp + (size_t)(wv * 16 + l16) * 256 + quad * 8;
  #pragma unroll
  for (int kk = 0; kk < 8; ++kk)
    pb4[kk] = *(const bf16x8*)(wr4 + kk * 32);
  const float pbias = proj_b[wv * 16 + l16];

  // ---------- Phase 3: attention. Wave -> (mt, hp). No intra-loop barriers. ----------
  unsigned short* sP = sX + hp * 4096;              // [64][64], XOR-swizzled (idx ^= (row&7)<<3)
  const float s2 = 0.17677669529663687f * 1.4426950408889634f;   // d^-0.5 * log2(e)
  const short onebf = (short)0x3F80;                // bf16 1.0
  const bf16x8 ones = {onebf, onebf, onebf, onebf, onebf, onebf, onebf, onebf};

  // q frags for both heads hoisted: after this, the wave's q rows are write-safe
  bf16x8 qa0 = *(const bf16x8*)(sQK + (16 * mt + l16) * QK_LD + (hp * 2 + 0) * 32 + quad * 8);
  bf16x8 qa1 = *(const bf16x8*)(sQK + (16 * mt + l16) * QK_LD + (hp * 2 + 1) * 32 + quad * 8);

  #pragma unroll
  for (int hh = 0; hh < 2; ++hh) {
    const int h = hp * 2 + hh;
    const bf16x8 qa = hh ? qa1 : qa0;
    bf16x8 kb[4];
    #pragma unroll
    for (int nt = 0; nt < 4; ++nt)
      kb[nt] = *(const bf16x8*)(sQK + (nt * 16 + l16) * QK_LD + 256 + h * 32 + quad * 8);
    f32x4 aq[4];
    #pragma unroll
    for (int nt = 0; nt < 4; ++nt)
      aq[nt] = __builtin_amdgcn_mfma_f32_16x16x32_bf16(qa, kb[nt], fz, 0, 0, 0);
    // exp2(logit) -> P (unnormalized), XOR-swizzled rows
    #pragma unroll
    for (int nt = 0; nt < 4; ++nt)
      #pragma unroll
      for (int r = 0; r < 4; ++r) {
        float ev = __builtin_amdgcn_exp2f(fmaf(aq[nt][r], s2, bf2f(bvx[hh][nt][r])));
        int row = 16 * mt + quad * 4 + r;
        sP[row * 64 + ((l16 + nt * 16) ^ ((row & 7) << 3))] = f2bf(ev);
      }
    // PV + row-sums: sums via MFMA against ones (lands in same (quad,r) layout as O)
    const int prow = 16 * mt + l16;
    const int ps = (l16 & 7) << 3;
    bf16x8 pa0 = *(const bf16x8*)(sP + prow * 64 + ((quad * 8) ^ ps));
    bf16x8 pa1 = *(const bf16x8*)(sP + prow * 64 + ((32 + quad * 8) ^ ps));
    bf16x8 vb00 = *(const bf16x8*)(sVT + (h * 32 + l16) * VT_LD + quad * 8);
    bf16x8 vb01 = *(const bf16x8*)(sVT + (h * 32 + l16) * VT_LD + 32 + quad * 8);
    bf16x8 vb10 = *(const bf16x8*)(sVT + (h * 32 + 16 + l16) * VT_LD + quad * 8);
    bf16x8 vb11 = *(const bf16x8*)(sVT + (h * 32 + 16 + l16) * VT_LD + 32 + quad * 8);
    f32x4 sa = fz, o0 = fz, o1 = fz;
    sa = __builtin_amdgcn_mfma_f32_16x16x32_bf16(pa0, ones, sa, 0, 0, 0);
    sa = __builtin_amdgcn_mfma_f32_16x16x32_bf16(pa1, ones, sa, 0, 0, 0);
    o0 = __builtin_amdgcn_mfma_f32_16x16x32_bf16(pa0, vb00, o0, 0, 0, 0);
    o0 = __builtin_amdgcn_mfma_f32_16x16x32_bf16(pa1, vb01, o0, 0, 0, 0);
    o1 = __builtin_amdgcn_mfma_f32_16x16x32_bf16(pa0, vb10, o1, 0, 0, 0);
    o1 = __builtin_amdgcn_mfma_f32_16x16x32_bf16(pa1, vb11, o1, 0, 0, 0);
    // normalized attn-out straight into this wave's OWN q rows (no barrier needed)
    #pragma unroll
    for (int r = 0; r < 4; ++r) {
      float iv = __builtin_amdgcn_rcpf(sa[r]);
      int orow = 16 * mt + quad * 4 + r;
      sQK[orow * QK_LD + h * 32 + l16]      = f2bf(o0[r] * iv);
      sQK[orow * QK_LD + h * 32 + 16 + l16] = f2bf(o1[r] * iv);
    }
  }
  __syncthreads();

  // ---------- Phase 4: final = attn_out @ Wproj^T (+b). Wave owns cols [16wv, 16wv+16) ----
  float* ob = out + (size_t)b * 16384;
  const int col4 = wv * 16 + l16;
  f32x4 acc4[4] = {fz, fz, fz, fz};
  #pragma unroll
  for (int kk = 0; kk < 8; ++kk)
    #pragma unroll
    for (int m = 0; m < 4; ++m) {
      bf16x8 a = *(const bf16x8*)(sQK + (16 * m + l16) * QK_LD + kk * 32 + quad * 8);
      acc4[m] = __builtin_amdgcn_mfma_f32_16x16x32_bf16(a, pb4[kk], acc4[m], 0, 0, 0);
    }
  #pragma unroll
  for (int m = 0; m < 4; ++m)
    #pragma unroll
    for (int r = 0; r < 4; ++r)
      ob[(16 * m + quad * 4 + r) * 256 + col4] = acc4[m][r] + pbias;
}

extern "C" void kernel_launch(void* const* d_in, const int* in_sizes, int n_in,
                              void* d_out, int out_size, void* d_ws, size_t ws_size,
                              hipStream_t stream) {
  const float* x      = (const float*)d_in[0];
  const float* qkv_w  = (const float*)d_in[1];   // [768][256]
  const float* qkv_b  = (const float*)d_in[2];   // [768]
  const float* proj_w = (const float*)d_in[3];   // [256][256]
  const float* proj_b = (const float*)d_in[4];   // [256]
  const float* table  = (const float*)d_in[5];   // [225][8]
  const int*   idx    = (const int*)d_in[6];     // [64][64]
  float* out = (float*)d_out;

  // ws layout: bf16 qkv_w (393216 B) | bf16 proj_w (131072 B) | bf16 bias [8][64][64] (65536 B)
  unsigned short* wq = (unsigned short*)d_ws;
  unsigned short* wp = wq + 196608;
  unsigned short* bm = wp + 65536;

  (void)hipFuncSetAttribute((const void*)lewin_kernel,
                            hipFuncAttributeMaxDynamicSharedMemorySize, SMEM_BYTES);

  prep_kernel<<<1152, 256, 0, stream>>>(qkv_w, proj_w, table, idx, wq, wp, bm);
  lewin_kernel<<<8192, 1024, SMEM_BYTES, stream>>>(x, wq, qkv_b, wp, proj_b, bm, out);
}